// Round 6
// baseline (357.871 us; speedup 1.0000x reference)
//
#include <hip/hip_runtime.h>
#include <hip/hip_bf16.h>

// Problem constants
#define BB 4
#define TT 2048
#define CC 1024
#define HH 16
#define DD 64

typedef __attribute__((ext_vector_type(8))) short short8;
typedef __attribute__((ext_vector_type(4))) float f32x4;

__device__ __forceinline__ float bf2f(short s) {
  unsigned u = ((unsigned)(unsigned short)s) << 16;
  float f;
  __builtin_memcpy(&f, &u, 4);
  return f;
}
__device__ __forceinline__ short f2bf(float f) {
  unsigned u;
  __builtin_memcpy(&u, &f, 4);
  u = (u + 0x7fffu + ((u >> 16) & 1u)) >> 16;
  return (short)u;
}

__device__ __forceinline__ unsigned cvt_pk_bf16(float lo, float hi) {
  unsigned r;
  asm("v_cvt_pk_bf16_f32 %0, %1, %2" : "=v"(r) : "v"(lo), "v"(hi));
  return r;
}

// hardware 2^x (v_exp_f32 IS base-2 per ISA)
__device__ __forceinline__ float exp2_fast(float x) {
  float r;
  asm("v_exp_f32 %0, %1" : "=v"(r) : "v"(x));
  return r;
}

template <int CTRL>
__device__ __forceinline__ float dpp_f(float v) {
  union { float f; int i; } u;
  u.f = v;
  u.i = __builtin_amdgcn_update_dpp(0, u.i, CTRL, 0xf, 0xf, true);
  return u.f;
}
// reduce across the 16-lane fr-group (DPP rows are 16 lanes)
__device__ __forceinline__ float rowmax16(float v) {
  v = fmaxf(v, dpp_f<0x128>(v));  // ror:8
  v = fmaxf(v, dpp_f<0x124>(v));  // ror:4
  v = fmaxf(v, dpp_f<0x4E>(v));   // quad_perm(2,3,0,1)
  v = fmaxf(v, dpp_f<0xB1>(v));   // quad_perm(1,0,3,2)
  return v;
}
__device__ __forceinline__ float rowsum16(float v) {
  v += dpp_f<0x128>(v);
  v += dpp_f<0x124>(v);
  v += dpp_f<0x4E>(v);
  v += dpp_f<0xB1>(v);
  return v;
}

__device__ __forceinline__ void gload_lds16(const void* g, void* l) {
  __builtin_amdgcn_global_load_lds(
      (const __attribute__((address_space(1))) void*)g,
      (__attribute__((address_space(3))) void*)l, 16, 0, 0);
}

// ---------------- cast fp32 -> bf16 (vectorized) ----------------
__global__ __launch_bounds__(256) void cast_bf16_kernel(
    const float* __restrict__ in, short* __restrict__ out, int n) {
  int i = (blockIdx.x * 256 + threadIdx.x) * 4;
  if (i >= n) return;
  float4 v = *(const float4*)&in[i];
  short4 o;
  o.x = f2bf(v.x); o.y = f2bf(v.y); o.z = f2bf(v.z); o.w = f2bf(v.w);
  *(short4*)&out[i] = o;
}

// ---------------- transpose + cast: [R][Cc] f32 -> [Cc][R] bf16 ----------------
__global__ __launch_bounds__(256) void transpose_cast_kernel(
    const float* __restrict__ in, short* __restrict__ out, int R, int Cc) {
  __shared__ float tile[32][33];
  const int tx = threadIdx.x, ty = threadIdx.y;  // 32 x 8
  const int c0 = blockIdx.x * 32, r0 = blockIdx.y * 32;
#pragma unroll
  for (int i = 0; i < 32; i += 8)
    tile[ty + i][tx] = in[(size_t)(r0 + ty + i) * Cc + c0 + tx];
  __syncthreads();
#pragma unroll
  for (int i = 0; i < 32; i += 8)
    out[(size_t)(c0 + ty + i) * R + r0 + tx] = f2bf(tile[tx][ty + i]);
}

// ---------------- bf16 MFMA GEMM: C[M,N] = A[M,K] * Bt[N,K]^T + bias ----------------
template <int MODE>
__global__ __launch_bounds__(256) void gemm_bf16(
    const short* __restrict__ A, const short* __restrict__ Bt,
    const float* __restrict__ bias, float* __restrict__ outF,
    short* __restrict__ outQ, short* __restrict__ outK, short* __restrict__ outV,
    int M, int N, int K) {
  __shared__ __align__(16) short As[128 * 32];
  __shared__ __align__(16) short Bs[128 * 32];
  const int tid = threadIdx.x;
  const int lane = tid & 63, wid = tid >> 6;
  const int wm = wid >> 1, wn = wid & 1;
  const int row0 = blockIdx.y * 128, col0 = blockIdx.x * 128;
  const int fr = lane & 15, fq = lane >> 4;
  const short* Ab = A + (size_t)row0 * K;
  const short* Bb = Bt + (size_t)col0 * K;
  const int sr = tid >> 2;
  const int so = (tid & 3) * 8;

  f32x4 acc[4][4];
#pragma unroll
  for (int m = 0; m < 4; ++m)
#pragma unroll
    for (int n = 0; n < 4; ++n) {
      f32x4 z = {0.f, 0.f, 0.f, 0.f};
      acc[m][n] = z;
    }

  for (int k0 = 0; k0 < K; k0 += 32) {
    __syncthreads();
    gload_lds16(Ab + (size_t)sr * K + k0 + so, &As[tid * 8]);
    gload_lds16(Ab + (size_t)(sr + 64) * K + k0 + so, &As[2048 + tid * 8]);
    gload_lds16(Bb + (size_t)sr * K + k0 + so, &Bs[tid * 8]);
    gload_lds16(Bb + (size_t)(sr + 64) * K + k0 + so, &Bs[2048 + tid * 8]);
    __syncthreads();
    short8 a[4], b[4];
#pragma unroll
    for (int m = 0; m < 4; ++m)
      a[m] = *(const short8*)&As[(wm * 64 + m * 16 + fr) * 32 + fq * 8];
#pragma unroll
    for (int n = 0; n < 4; ++n)
      b[n] = *(const short8*)&Bs[(wn * 64 + n * 16 + fr) * 32 + fq * 8];
#pragma unroll
    for (int m = 0; m < 4; ++m)
#pragma unroll
      for (int n = 0; n < 4; ++n)
        acc[m][n] = __builtin_amdgcn_mfma_f32_16x16x32_bf16(a[m], b[n], acc[m][n], 0, 0, 0);
  }

  float bv[4];
#pragma unroll
  for (int n = 0; n < 4; ++n) bv[n] = bias[col0 + wn * 64 + n * 16 + fr];

  if (MODE == 0) {
#pragma unroll
    for (int m = 0; m < 4; ++m) {
      const int grow = row0 + wm * 64 + m * 16 + fq * 4;
#pragma unroll
      for (int n = 0; n < 4; ++n) {
        const int gcol = col0 + wn * 64 + n * 16 + fr;
#pragma unroll
        for (int r = 0; r < 4; ++r)
          outF[(size_t)(grow + r) * N + gcol] = acc[m][n][r] + bv[n];
      }
    }
  } else {
#pragma unroll
    for (int n = 0; n < 4; ++n) {
      const int gcol = col0 + wn * 64 + n * 16 + fr;
      const int which = gcol >> 10;
      const int h = (gcol & 1023) >> 6;
      const int d = gcol & 63;
      short* dst = (which == 0) ? outQ : (which == 1) ? outK : outV;
#pragma unroll
      for (int m = 0; m < 4; ++m) {
        const int grow = row0 + wm * 64 + m * 16 + fq * 4;
#pragma unroll
        for (int r = 0; r < 4; ++r) {
          const int gb = (grow + r) >> 11;
          const int gt = (grow + r) & 2047;
          const int bh = gb * HH + h;
          size_t idx;
          if (which == 2)
            idx = ((size_t)bh * DD + d) * TT + gt;   // Vt: [BH, D, T]
          else
            idx = ((size_t)bh * TT + gt) * DD + d;   // Q,K: [BH, T, D]
          dst[idx] = f2bf(acc[m][n][r] + bv[n]);
        }
      }
    }
  }
}

// ---------------- MFMA flash attention, v3: no K/V staging ----------------
// K and Vt fragments are consumed in per-lane-contiguous 16B patterns, and
// each XCD's working set (8 heads x 512KB K+V via bh = lin&63 pinning) exactly
// fits one 4MB L2 -> load fragments DIRECT from global, no LDS staging, NO
// barriers at all. Waves fully independent (qt = 15 - lin>>6 heavy-first).
// Softmax: base-2, DPP 16-lane reduces, defer-rescale, cvt_pk P-pack into
// wave-private swizzled LDS (the only LDS use, 16KB/block).
#define C2 0.18033688f  // 0.125 * log2(e)

__global__ __launch_bounds__(256) void attn_mfma_kernel(
    const short* __restrict__ q,   // [BH, T, D]
    const short* __restrict__ k,   // [BH, T, D]
    const short* __restrict__ vt,  // [BH, D, T]
    short* __restrict__ ctx) {     // [B*T, C]
  __shared__ __align__(16) short Ps[4][32 * 64];
  const int tid = threadIdx.x, lane = tid & 63, wid = tid >> 6;
  const int fr = lane & 15, fq = lane >> 4;
  const int lin = blockIdx.x;
  const int bh = lin & 63;
  const int qt = 15 - (lin >> 6);
  const int qw0 = qt * 128 + wid * 32;
  const short* kbp = k + (size_t)bh * TT * DD;
  const short* vbp = vt + (size_t)bh * DD * TT;
  char* PsB = (char*)&Ps[wid][0];

  // Q fragments (persistent)
  short8 aq[2][2];
#pragma unroll
  for (int m = 0; m < 2; ++m)
#pragma unroll
    for (int ks = 0; ks < 2; ++ks)
      aq[m][ks] = *(const short8*)&q[((size_t)bh * TT + qw0 + m * 16 + fr) * DD + ks * 32 + fq * 8];

  float M[2][4], L[2][4];
  f32x4 o[2][4];
#pragma unroll
  for (int m = 0; m < 2; ++m)
#pragma unroll
    for (int r = 0; r < 4; ++r) { M[m][r] = -1e30f; L[m][r] = 0.f; }
#pragma unroll
  for (int m = 0; m < 2; ++m)
#pragma unroll
    for (int dg = 0; dg < 4; ++dg) {
      f32x4 z = {0.f, 0.f, 0.f, 0.f};
      o[m][dg] = z;
    }

  const int ntw = (qw0 >> 6) + 1;  // KV-64 tiles for this wave

  for (int t = 0; t < ntw; ++t) {
    const int kv0s = t * 64;
    const bool domask = (kv0s + 63 > qw0);

    // ---- K fragments direct from global (L2) ----
    short8 bk[4][2];
#pragma unroll
    for (int n = 0; n < 4; ++n)
#pragma unroll
      for (int ks = 0; ks < 2; ++ks)
        bk[n][ks] = *(const short8*)&kbp[(size_t)(kv0s + n * 16 + fr) * DD + ks * 32 + fq * 8];

    // ---- QK^T ----
    f32x4 s[2][4];
    __builtin_amdgcn_s_setprio(1);
#pragma unroll
    for (int m = 0; m < 2; ++m)
#pragma unroll
      for (int n = 0; n < 4; ++n) {
        f32x4 z = {0.f, 0.f, 0.f, 0.f};
        s[m][n] = z;
#pragma unroll
        for (int ks = 0; ks < 2; ++ks)
          s[m][n] = __builtin_amdgcn_mfma_f32_16x16x32_bf16(aq[m][ks], bk[n][ks], s[m][n], 0, 0, 0);
      }
    __builtin_amdgcn_s_setprio(0);

    // ---- V fragments direct from global (issued early, consumed after softmax) ----
    short8 bv[4][2];
#pragma unroll
    for (int dg = 0; dg < 4; ++dg)
#pragma unroll
      for (int ks = 0; ks < 2; ++ks)
        bv[dg][ks] = *(const short8*)&vbp[(size_t)(dg * 16 + fr) * TT + kv0s + ks * 32 + fq * 8];

    // ---- causal mask (diagonal tiles only) ----
    if (domask) {
#pragma unroll
      for (int m = 0; m < 2; ++m)
#pragma unroll
        for (int n = 0; n < 4; ++n)
#pragma unroll
          for (int r = 0; r < 4; ++r) {
            const int qq = qw0 + m * 16 + fq * 4 + r;
            const int kk = kv0s + n * 16 + fr;
            if (kk > qq) s[m][n][r] = -1e30f;
          }
    }

    // ---- online softmax (base-2, defer-rescale, DPP reduce) ----
#pragma unroll
    for (int m = 0; m < 2; ++m) {
      float rm2[4];
#pragma unroll
      for (int r = 0; r < 4; ++r) {
        float rm = fmaxf(fmaxf(s[m][0][r], s[m][1][r]), fmaxf(s[m][2][r], s[m][3][r]));
        rm2[r] = rowmax16(rm) * C2;
      }
      float dmax = fmaxf(fmaxf(rm2[0] - M[m][0], rm2[1] - M[m][1]),
                         fmaxf(rm2[2] - M[m][2], rm2[3] - M[m][3]));
      if (__any(dmax > 8.0f)) {
#pragma unroll
        for (int r = 0; r < 4; ++r) {
          const float Mn = fmaxf(M[m][r], rm2[r]);
          const float corr = exp2_fast(M[m][r] - Mn);
          M[m][r] = Mn;
          L[m][r] *= corr;
#pragma unroll
          for (int dg = 0; dg < 4; ++dg) o[m][dg][r] *= corr;
        }
      }
      float psum[4] = {0.f, 0.f, 0.f, 0.f};
      const int brow = m * 16 + fq * 4;
      unsigned short* pw = (unsigned short*)PsB;
#pragma unroll
      for (int n = 0; n < 4; ++n) {
        const float p0 = exp2_fast(__builtin_fmaf(s[m][n][0], C2, -M[m][0]));
        const float p1 = exp2_fast(__builtin_fmaf(s[m][n][1], C2, -M[m][1]));
        const float p2 = exp2_fast(__builtin_fmaf(s[m][n][2], C2, -M[m][2]));
        const float p3 = exp2_fast(__builtin_fmaf(s[m][n][3], C2, -M[m][3]));
        psum[0] += p0; psum[1] += p1; psum[2] += p2; psum[3] += p3;
        const unsigned u0 = cvt_pk_bf16(p0, p1);
        const unsigned u1 = cvt_pk_bf16(p2, p3);
        const int colb = n * 32 + fr * 2;
        pw[((brow + 0) * 128 + (colb ^ (((brow + 0) & 7) << 4))) >> 1] = (unsigned short)u0;
        pw[((brow + 1) * 128 + (colb ^ (((brow + 1) & 7) << 4))) >> 1] = (unsigned short)(u0 >> 16);
        pw[((brow + 2) * 128 + (colb ^ (((brow + 2) & 7) << 4))) >> 1] = (unsigned short)u1;
        pw[((brow + 3) * 128 + (colb ^ (((brow + 3) & 7) << 4))) >> 1] = (unsigned short)(u1 >> 16);
      }
#pragma unroll
      for (int r = 0; r < 4; ++r) L[m][r] += rowsum16(psum[r]);
    }

    // ---- PV ----
    short8 ap[2][2];
#pragma unroll
    for (int m = 0; m < 2; ++m) {
      const int qrow = m * 16 + fr;
#pragma unroll
      for (int ks = 0; ks < 2; ++ks)
        ap[m][ks] = *(const short8*)(PsB + qrow * 128 +
                                     (((ks * 64 + fq * 16) ^ ((qrow & 7) << 4))));
    }
    __builtin_amdgcn_s_setprio(1);
#pragma unroll
    for (int m = 0; m < 2; ++m)
#pragma unroll
      for (int dg = 0; dg < 4; ++dg)
#pragma unroll
        for (int ks = 0; ks < 2; ++ks)
          o[m][dg] = __builtin_amdgcn_mfma_f32_16x16x32_bf16(ap[m][ks], bv[dg][ks], o[m][dg], 0, 0, 0);
    __builtin_amdgcn_s_setprio(0);
  }

  // ---- epilogue ----
  const int b = bh >> 4, h = bh & 15;
#pragma unroll
  for (int m = 0; m < 2; ++m)
#pragma unroll
    for (int dg = 0; dg < 4; ++dg)
#pragma unroll
      for (int r = 0; r < 4; ++r) {
        const int qq = qw0 + m * 16 + fq * 4 + r;
        ctx[((size_t)(b * TT + qq)) * CC + h * DD + dg * 16 + fr] =
            f2bf(o[m][dg][r] / L[m][r]);
      }
}

// ---------------- launch ----------------
extern "C" void kernel_launch(void* const* d_in, const int* in_sizes, int n_in,
                              void* d_out, int out_size, void* d_ws, size_t ws_size,
                              hipStream_t stream) {
  (void)in_sizes; (void)n_in; (void)out_size; (void)ws_size;
  const float* x = (const float*)d_in[0];
  const float* w_qkv = (const float*)d_in[1];
  const float* b_qkv = (const float*)d_in[2];
  const float* w_out = (const float*)d_in[3];
  const float* b_out = (const float*)d_in[4];
  float* out = (float*)d_out;

  char* w = (char*)d_ws;
  short* xb    = (short*)w; w += (size_t)BB * TT * CC * 2;
  short* wqkvT = (short*)w; w += (size_t)3 * CC * CC * 2;
  short* woutT = (short*)w; w += (size_t)CC * CC * 2;
  short* qb    = (short*)w; w += (size_t)BB * HH * TT * DD * 2;
  short* kb    = (short*)w; w += (size_t)BB * HH * TT * DD * 2;
  short* vtb   = (short*)w; w += (size_t)BB * HH * DD * TT * 2;
  short* ctx   = (short*)w; w += (size_t)BB * TT * CC * 2;

  const int M = BB * TT;  // 8192

  cast_bf16_kernel<<<dim3((M * CC) / 4 / 256), dim3(256), 0, stream>>>(x, xb, M * CC);
  transpose_cast_kernel<<<dim3(3 * CC / 32, CC / 32), dim3(32, 8), 0, stream>>>(
      w_qkv, wqkvT, CC, 3 * CC);
  transpose_cast_kernel<<<dim3(CC / 32, CC / 32), dim3(32, 8), 0, stream>>>(
      w_out, woutT, CC, CC);

  gemm_bf16<1><<<dim3((3 * CC) / 128, M / 128), dim3(256), 0, stream>>>(
      xb, wqkvT, b_qkv, nullptr, qb, kb, vtb, M, 3 * CC, CC);

  attn_mfma_kernel<<<dim3(16 * 64), dim3(256), 0, stream>>>(qb, kb, vtb, ctx);

  gemm_bf16<0><<<dim3(CC / 128, M / 128), dim3(256), 0, stream>>>(
      ctx, woutT, b_out, out, nullptr, nullptr, nullptr, M, CC, CC);
}

// Round 8
// 296.558 us; speedup vs baseline: 1.2067x; 1.2067x over previous
//
#include <hip/hip_runtime.h>
#include <hip/hip_bf16.h>

// Problem constants
#define BB 4
#define TT 2048
#define CC 1024
#define HH 16
#define DD 64

typedef __attribute__((ext_vector_type(8))) short short8;
typedef __attribute__((ext_vector_type(4))) float f32x4;

__device__ __forceinline__ float bf2f(short s) {
  unsigned u = ((unsigned)(unsigned short)s) << 16;
  float f;
  __builtin_memcpy(&f, &u, 4);
  return f;
}
__device__ __forceinline__ short f2bf(float f) {
  unsigned u;
  __builtin_memcpy(&u, &f, 4);
  u = (u + 0x7fffu + ((u >> 16) & 1u)) >> 16;
  return (short)u;
}

__device__ __forceinline__ unsigned cvt_pk_bf16(float lo, float hi) {
  unsigned r;
  asm("v_cvt_pk_bf16_f32 %0, %1, %2" : "=v"(r) : "v"(lo), "v"(hi));
  return r;
}

// hardware 2^x (v_exp_f32 IS base-2 per ISA)
__device__ __forceinline__ float exp2_fast(float x) {
  float r;
  asm("v_exp_f32 %0, %1" : "=v"(r) : "v"(x));
  return r;
}

template <int CTRL>
__device__ __forceinline__ float dpp_f(float v) {
  union { float f; int i; } u;
  u.f = v;
  u.i = __builtin_amdgcn_update_dpp(0, u.i, CTRL, 0xf, 0xf, true);
  return u.f;
}
// reduce across the 16-lane fr-group (DPP rows are 16 lanes)
__device__ __forceinline__ float rowmax16(float v) {
  v = fmaxf(v, dpp_f<0x128>(v));  // ror:8
  v = fmaxf(v, dpp_f<0x124>(v));  // ror:4
  v = fmaxf(v, dpp_f<0x4E>(v));   // quad_perm(2,3,0,1)
  v = fmaxf(v, dpp_f<0xB1>(v));   // quad_perm(1,0,3,2)
  return v;
}
__device__ __forceinline__ float rowsum16(float v) {
  v += dpp_f<0x128>(v);
  v += dpp_f<0x124>(v);
  v += dpp_f<0x4E>(v);
  v += dpp_f<0xB1>(v);
  return v;
}

__device__ __forceinline__ void gload_lds16(const void* g, void* l) {
  __builtin_amdgcn_global_load_lds(
      (const __attribute__((address_space(1))) void*)g,
      (__attribute__((address_space(3))) void*)l, 16, 0, 0);
}

// ---------------- cast fp32 -> bf16 (vectorized) ----------------
__global__ __launch_bounds__(256) void cast_bf16_kernel(
    const float* __restrict__ in, short* __restrict__ out, int n) {
  int i = (blockIdx.x * 256 + threadIdx.x) * 4;
  if (i >= n) return;
  float4 v = *(const float4*)&in[i];
  short4 o;
  o.x = f2bf(v.x); o.y = f2bf(v.y); o.z = f2bf(v.z); o.w = f2bf(v.w);
  *(short4*)&out[i] = o;
}

// ---------------- transpose + cast: [R][Cc] f32 -> [Cc][R] bf16 ----------------
__global__ __launch_bounds__(256) void transpose_cast_kernel(
    const float* __restrict__ in, short* __restrict__ out, int R, int Cc) {
  __shared__ float tile[32][33];
  const int tx = threadIdx.x, ty = threadIdx.y;  // 32 x 8
  const int c0 = blockIdx.x * 32, r0 = blockIdx.y * 32;
#pragma unroll
  for (int i = 0; i < 32; i += 8)
    tile[ty + i][tx] = in[(size_t)(r0 + ty + i) * Cc + c0 + tx];
  __syncthreads();
#pragma unroll
  for (int i = 0; i < 32; i += 8)
    out[(size_t)(c0 + ty + i) * R + r0 + tx] = f2bf(tile[tx][ty + i]);
}

// ---------------- V transpose: [BH,T,D] bf16 -> [BH,D,T] bf16 ----------------
__global__ __launch_bounds__(256) void v_transpose_kernel(
    const short* __restrict__ vb, short* __restrict__ vt) {
  __shared__ int tile[32][33];
  const int tx = threadIdx.x, ty = threadIdx.y;  // 32 x 8
  const int bh = blockIdx.z;
  const int d0 = blockIdx.x * 32, t0 = blockIdx.y * 32;
  const short* src = vb + (size_t)bh * TT * DD;
  short* dstp = vt + (size_t)bh * DD * TT;
#pragma unroll
  for (int i = 0; i < 32; i += 8)
    tile[ty + i][tx] = src[(size_t)(t0 + ty + i) * DD + d0 + tx];
  __syncthreads();
#pragma unroll
  for (int i = 0; i < 32; i += 8)
    dstp[(size_t)(d0 + ty + i) * TT + t0 + tx] = (short)tile[tx][ty + i];
}

// ---------------- bf16 MFMA GEMM: C[M,N] = A[M,K] * Bt[N,K]^T + bias ----------------
// MODE 0: fp32 out. MODE 1: QKV scatter, all three in natural [BH,T,D] bf16
// (V transposed to [BH,D,T] by a separate kernel -> coalesced epilogue).
template <int MODE>
__global__ __launch_bounds__(256) void gemm_bf16(
    const short* __restrict__ A, const short* __restrict__ Bt,
    const float* __restrict__ bias, float* __restrict__ outF,
    short* __restrict__ outQ, short* __restrict__ outK, short* __restrict__ outV,
    int M, int N, int K) {
  __shared__ __align__(16) short As[128 * 32];
  __shared__ __align__(16) short Bs[128 * 32];
  const int tid = threadIdx.x;
  const int lane = tid & 63, wid = tid >> 6;
  const int wm = wid >> 1, wn = wid & 1;
  const int row0 = blockIdx.y * 128, col0 = blockIdx.x * 128;
  const int fr = lane & 15, fq = lane >> 4;
  const short* Ab = A + (size_t)row0 * K;
  const short* Bb = Bt + (size_t)col0 * K;
  const int sr = tid >> 2;
  const int so = (tid & 3) * 8;

  f32x4 acc[4][4];
#pragma unroll
  for (int m = 0; m < 4; ++m)
#pragma unroll
    for (int n = 0; n < 4; ++n) {
      f32x4 z = {0.f, 0.f, 0.f, 0.f};
      acc[m][n] = z;
    }

  for (int k0 = 0; k0 < K; k0 += 32) {
    __syncthreads();
    gload_lds16(Ab + (size_t)sr * K + k0 + so, &As[tid * 8]);
    gload_lds16(Ab + (size_t)(sr + 64) * K + k0 + so, &As[2048 + tid * 8]);
    gload_lds16(Bb + (size_t)sr * K + k0 + so, &Bs[tid * 8]);
    gload_lds16(Bb + (size_t)(sr + 64) * K + k0 + so, &Bs[2048 + tid * 8]);
    __syncthreads();
    short8 a[4], b[4];
#pragma unroll
    for (int m = 0; m < 4; ++m)
      a[m] = *(const short8*)&As[(wm * 64 + m * 16 + fr) * 32 + fq * 8];
#pragma unroll
    for (int n = 0; n < 4; ++n)
      b[n] = *(const short8*)&Bs[(wn * 64 + n * 16 + fr) * 32 + fq * 8];
#pragma unroll
    for (int m = 0; m < 4; ++m)
#pragma unroll
      for (int n = 0; n < 4; ++n)
        acc[m][n] = __builtin_amdgcn_mfma_f32_16x16x32_bf16(a[m], b[n], acc[m][n], 0, 0, 0);
  }

  float bv[4];
#pragma unroll
  for (int n = 0; n < 4; ++n) bv[n] = bias[col0 + wn * 64 + n * 16 + fr];

  if (MODE == 0) {
#pragma unroll
    for (int m = 0; m < 4; ++m) {
      const int grow = row0 + wm * 64 + m * 16 + fq * 4;
#pragma unroll
      for (int n = 0; n < 4; ++n) {
        const int gcol = col0 + wn * 64 + n * 16 + fr;
#pragma unroll
        for (int r = 0; r < 4; ++r)
          outF[(size_t)(grow + r) * N + gcol] = acc[m][n][r] + bv[n];
      }
    }
  } else {
#pragma unroll
    for (int n = 0; n < 4; ++n) {
      const int gcol = col0 + wn * 64 + n * 16 + fr;
      const int which = gcol >> 10;
      const int h = (gcol & 1023) >> 6;
      const int d = gcol & 63;
      short* dst = (which == 0) ? outQ : (which == 1) ? outK : outV;
#pragma unroll
      for (int m = 0; m < 4; ++m) {
        const int grow = row0 + wm * 64 + m * 16 + fq * 4;
#pragma unroll
        for (int r = 0; r < 4; ++r) {
          const int gb = (grow + r) >> 11;
          const int gt = (grow + r) & 2047;
          const int bh = gb * HH + h;
          dst[((size_t)bh * TT + gt) * DD + d] = f2bf(acc[m][n][r] + bv[n]);
        }
      }
    }
  }
}

// ---------------- MFMA flash attention (round-5 verified version) ----------------
// Grid: 1024 1-D blocks; bh = lin&63 (pins each head's K/V to one XCD L2),
// qt = 15 - lin>>6 (heavy q-tiles dispatch first).
// Block: 4 waves x 32 q-rows = 128-row Q tile. KV-tile 128, double-buffered
// LDS (K [128][64], Vt [64][128], XOR-swizzled), single s_barrier + vmcnt(0)
// per tile with stage-issue-before-compute. Two KV-64 substeps per tile.
// Softmax: base-2, DPP 16-lane reductions, defer-rescale (THR=8 in log2),
// P packed via v_cvt_pk_bf16_f32 into wave-private swizzled LDS.
#define C2 0.18033688f  // 0.125 * log2(e)

__global__ __launch_bounds__(256) void attn_mfma_kernel(
    const short* __restrict__ q,   // [BH, T, D]
    const short* __restrict__ k,   // [BH, T, D]
    const short* __restrict__ vt,  // [BH, D, T]
    short* __restrict__ ctx) {     // [B*T, C]
  __shared__ __align__(16) short Ks[2][128 * 64];
  __shared__ __align__(16) short Vs[2][64 * 128];
  __shared__ __align__(16) short Ps[4][32 * 64];
  const int tid = threadIdx.x, lane = tid & 63, wid = tid >> 6;
  const int fr = lane & 15, fq = lane >> 4;
  const int lin = blockIdx.x;
  const int bh = lin & 63;
  const int qt = 15 - (lin >> 6);
  const int q0 = qt * 128;
  const int qw0 = q0 + wid * 32;
  const short* kbp = k + (size_t)bh * TT * DD;
  const short* vbp = vt + (size_t)bh * DD * TT;
  char* PsB = (char*)&Ps[wid][0];

#define KSB(c) ((char*)&Ks[0][0] + (c) * (128 * 64 * 2))
#define VSB(c) ((char*)&Vs[0][0] + (c) * (64 * 128 * 2))

  // Q fragments (persistent)
  short8 aq[2][2];
#pragma unroll
  for (int m = 0; m < 2; ++m)
#pragma unroll
    for (int ks = 0; ks < 2; ++ks)
      aq[m][ks] = *(const short8*)&q[((size_t)bh * TT + qw0 + m * 16 + fr) * DD + ks * 32 + fq * 8];

  float M[2][4], L[2][4];
  f32x4 o[2][4];
#pragma unroll
  for (int m = 0; m < 2; ++m)
#pragma unroll
    for (int r = 0; r < 4; ++r) { M[m][r] = -1e30f; L[m][r] = 0.f; }
#pragma unroll
  for (int m = 0; m < 2; ++m)
#pragma unroll
    for (int dg = 0; dg < 4; ++dg) {
      f32x4 z = {0.f, 0.f, 0.f, 0.f};
      o[m][dg] = z;
    }

  const int nt = qt + 1;

#define STAGE(c, tt)                                                           \
  do {                                                                         \
    const int kv0_ = (tt) * 128;                                               \
    _Pragma("unroll") for (int b_ = 0; b_ < 4; ++b_) {                         \
      const int lo_ = b_ * 4096 + tid * 16;                                    \
      const int row_ = lo_ >> 7;                                               \
      const int colb_ = lo_ & 127;                                             \
      const int src_ = colb_ ^ ((row_ & 7) << 4);                              \
      gload_lds16(kbp + ((size_t)(kv0_ + row_)) * DD + (src_ >> 1),            \
                  KSB(c) + lo_);                                               \
    }                                                                          \
    _Pragma("unroll") for (int b_ = 0; b_ < 4; ++b_) {                         \
      const int lo_ = b_ * 4096 + tid * 16;                                    \
      const int row_ = lo_ >> 8;                                               \
      const int colb_ = lo_ & 255;                                             \
      const int src_ = colb_ ^ ((row_ & 7) << 4);                              \
      gload_lds16(vbp + (size_t)row_ * TT + kv0_ + (src_ >> 1),                \
                  VSB(c) + lo_);                                               \
    }                                                                          \
  } while (0)

  STAGE(0, 0);

  for (int t = 0; t < nt; ++t) {
    const int cur = t & 1;
    asm volatile("s_waitcnt vmcnt(0)" ::: "memory");
    __builtin_amdgcn_s_barrier();
    if (t + 1 < nt) STAGE(cur ^ 1, t + 1);
    const int kv0 = t * 128;
    if (kv0 > qw0 + 31) continue;

#pragma unroll
    for (int sub = 0; sub < 2; ++sub) {
      const int kv0s = kv0 + sub * 64;
      if (kv0s > qw0 + 31) continue;
      const bool domask = (kv0s + 63 > qw0);

      // ---- QK^T ----
      short8 bk[4][2];
#pragma unroll
      for (int n = 0; n < 4; ++n) {
        const int row = sub * 64 + n * 16 + fr;
#pragma unroll
        for (int ks = 0; ks < 2; ++ks)
          bk[n][ks] = *(const short8*)(KSB(cur) + row * 128 +
                                       (((ks * 64 + fq * 16) ^ ((row & 7) << 4))));
      }
      f32x4 s[2][4];
      __builtin_amdgcn_s_setprio(1);
#pragma unroll
      for (int m = 0; m < 2; ++m)
#pragma unroll
        for (int n = 0; n < 4; ++n) {
          f32x4 z = {0.f, 0.f, 0.f, 0.f};
          s[m][n] = z;
#pragma unroll
          for (int ks = 0; ks < 2; ++ks)
            s[m][n] = __builtin_amdgcn_mfma_f32_16x16x32_bf16(aq[m][ks], bk[n][ks], s[m][n], 0, 0, 0);
        }
      __builtin_amdgcn_s_setprio(0);

      if (domask) {
#pragma unroll
        for (int m = 0; m < 2; ++m)
#pragma unroll
          for (int n = 0; n < 4; ++n)
#pragma unroll
            for (int r = 0; r < 4; ++r) {
              const int qq = qw0 + m * 16 + fq * 4 + r;
              const int kk = kv0s + n * 16 + fr;
              if (kk > qq) s[m][n][r] = -1e30f;
            }
      }

      // ---- online softmax (base-2, defer-rescale, DPP reduce) ----
#pragma unroll
      for (int m = 0; m < 2; ++m) {
        float rm2[4];
#pragma unroll
        for (int r = 0; r < 4; ++r) {
          float rm = fmaxf(fmaxf(s[m][0][r], s[m][1][r]), fmaxf(s[m][2][r], s[m][3][r]));
          rm2[r] = rowmax16(rm) * C2;
        }
        float dmax = fmaxf(fmaxf(rm2[0] - M[m][0], rm2[1] - M[m][1]),
                           fmaxf(rm2[2] - M[m][2], rm2[3] - M[m][3]));
        if (__any(dmax > 8.0f)) {
#pragma unroll
          for (int r = 0; r < 4; ++r) {
            const float Mn = fmaxf(M[m][r], rm2[r]);
            const float corr = exp2_fast(M[m][r] - Mn);
            M[m][r] = Mn;
            L[m][r] *= corr;
#pragma unroll
            for (int dg = 0; dg < 4; ++dg) o[m][dg][r] *= corr;
          }
        }
        float psum[4] = {0.f, 0.f, 0.f, 0.f};
        const int brow = m * 16 + fq * 4;
        unsigned short* pw = (unsigned short*)PsB;
#pragma unroll
        for (int n = 0; n < 4; ++n) {
          const float p0 = exp2_fast(__builtin_fmaf(s[m][n][0], C2, -M[m][0]));
          const float p1 = exp2_fast(__builtin_fmaf(s[m][n][1], C2, -M[m][1]));
          const float p2 = exp2_fast(__builtin_fmaf(s[m][n][2], C2, -M[m][2]));
          const float p3 = exp2_fast(__builtin_fmaf(s[m][n][3], C2, -M[m][3]));
          psum[0] += p0; psum[1] += p1; psum[2] += p2; psum[3] += p3;
          const unsigned u0 = cvt_pk_bf16(p0, p1);
          const unsigned u1 = cvt_pk_bf16(p2, p3);
          const int colb = n * 32 + fr * 2;
          pw[((brow + 0) * 128 + (colb ^ (((brow + 0) & 7) << 4))) >> 1] = (unsigned short)u0;
          pw[((brow + 1) * 128 + (colb ^ (((brow + 1) & 7) << 4))) >> 1] = (unsigned short)(u0 >> 16);
          pw[((brow + 2) * 128 + (colb ^ (((brow + 2) & 7) << 4))) >> 1] = (unsigned short)u1;
          pw[((brow + 3) * 128 + (colb ^ (((brow + 3) & 7) << 4))) >> 1] = (unsigned short)(u1 >> 16);
        }
#pragma unroll
        for (int r = 0; r < 4; ++r) L[m][r] += rowsum16(psum[r]);
      }

      // ---- PV ----
      short8 ap[2][2], bv[4][2];
#pragma unroll
      for (int m = 0; m < 2; ++m) {
        const int qrow = m * 16 + fr;
#pragma unroll
        for (int ks = 0; ks < 2; ++ks)
          ap[m][ks] = *(const short8*)(PsB + qrow * 128 +
                                       (((ks * 64 + fq * 16) ^ ((qrow & 7) << 4))));
      }
#pragma unroll
      for (int dg = 0; dg < 4; ++dg) {
        const int row = dg * 16 + fr;
#pragma unroll
        for (int ks = 0; ks < 2; ++ks)
          bv[dg][ks] = *(const short8*)(VSB(cur) + row * 256 +
                                        (((sub * 128 + ks * 64 + fq * 16) ^ ((row & 7) << 4))));
      }
      __builtin_amdgcn_s_setprio(1);
#pragma unroll
      for (int m = 0; m < 2; ++m)
#pragma unroll
        for (int dg = 0; dg < 4; ++dg)
#pragma unroll
          for (int ks = 0; ks < 2; ++ks)
            o[m][dg] = __builtin_amdgcn_mfma_f32_16x16x32_bf16(ap[m][ks], bv[dg][ks], o[m][dg], 0, 0, 0);
      __builtin_amdgcn_s_setprio(0);
    }
  }

  // ---- epilogue ----
  const int b = bh >> 4, h = bh & 15;
#pragma unroll
  for (int m = 0; m < 2; ++m)
#pragma unroll
    for (int dg = 0; dg < 4; ++dg)
#pragma unroll
      for (int r = 0; r < 4; ++r) {
        const int qq = qw0 + m * 16 + fq * 4 + r;
        ctx[((size_t)(b * TT + qq)) * CC + h * DD + dg * 16 + fr] =
            f2bf(o[m][dg][r] / L[m][r]);
      }
}

// ---------------- launch ----------------
extern "C" void kernel_launch(void* const* d_in, const int* in_sizes, int n_in,
                              void* d_out, int out_size, void* d_ws, size_t ws_size,
                              hipStream_t stream) {
  (void)in_sizes; (void)n_in; (void)out_size; (void)ws_size;
  const float* x = (const float*)d_in[0];
  const float* w_qkv = (const float*)d_in[1];
  const float* b_qkv = (const float*)d_in[2];
  const float* w_out = (const float*)d_in[3];
  const float* b_out = (const float*)d_in[4];
  float* out = (float*)d_out;

  char* w = (char*)d_ws;
  short* xb    = (short*)w; w += (size_t)BB * TT * CC * 2;        // 16 MB
  short* wqkvT = (short*)w; w += (size_t)3 * CC * CC * 2;         // 6 MB
  short* woutT = (short*)w; w += (size_t)CC * CC * 2;             // 2 MB
  short* qb    = (short*)w; w += (size_t)BB * HH * TT * DD * 2;   // 16 MB
  short* kb    = (short*)w; w += (size_t)BB * HH * TT * DD * 2;   // 16 MB
  short* vtb   = (short*)w; w += (size_t)BB * HH * DD * TT * 2;   // 16 MB
  short* ctx   = (short*)w; w += (size_t)BB * TT * CC * 2;        // 16 MB

  const int M = BB * TT;  // 8192

  cast_bf16_kernel<<<dim3((M * CC) / 4 / 256), dim3(256), 0, stream>>>(x, xb, M * CC);
  transpose_cast_kernel<<<dim3(3 * CC / 32, CC / 32), dim3(32, 8), 0, stream>>>(
      w_qkv, wqkvT, CC, 3 * CC);
  transpose_cast_kernel<<<dim3(CC / 32, CC / 32), dim3(32, 8), 0, stream>>>(
      w_out, woutT, CC, CC);

  // QKV projection. V (natural [BH,T,D]) goes into ctx as temp storage;
  // v_transpose then produces vtb [BH,D,T]; attn overwrites ctx afterwards.
  gemm_bf16<1><<<dim3((3 * CC) / 128, M / 128), dim3(256), 0, stream>>>(
      xb, wqkvT, b_qkv, nullptr, qb, kb, ctx, M, 3 * CC, CC);

  v_transpose_kernel<<<dim3(DD / 32, TT / 32, BB * HH), dim3(32, 8), 0, stream>>>(
      ctx, vtb);

  attn_mfma_kernel<<<dim3(16 * 64), dim3(256), 0, stream>>>(qb, kb, vtb, ctx);

  gemm_bf16<0><<<dim3(CC / 128, M / 128), dim3(256), 0, stream>>>(
      ctx, woutT, b_out, out, nullptr, nullptr, nullptr, M, CC, CC);
}

// Round 9
// 287.753 us; speedup vs baseline: 1.2437x; 1.0306x over previous
//
#include <hip/hip_runtime.h>
#include <hip/hip_bf16.h>

// Problem constants
#define BB 4
#define TT 2048
#define CC 1024
#define HH 16
#define DD 64

typedef __attribute__((ext_vector_type(8))) short short8;
typedef __attribute__((ext_vector_type(4))) float f32x4;

__device__ __forceinline__ float bf2f(short s) {
  unsigned u = ((unsigned)(unsigned short)s) << 16;
  float f;
  __builtin_memcpy(&f, &u, 4);
  return f;
}
__device__ __forceinline__ short f2bf(float f) {
  unsigned u;
  __builtin_memcpy(&u, &f, 4);
  u = (u + 0x7fffu + ((u >> 16) & 1u)) >> 16;
  return (short)u;
}

__device__ __forceinline__ unsigned cvt_pk_bf16(float lo, float hi) {
  unsigned r;
  asm("v_cvt_pk_bf16_f32 %0, %1, %2" : "=v"(r) : "v"(lo), "v"(hi));
  return r;
}

// hardware 2^x (v_exp_f32 IS base-2 per ISA)
__device__ __forceinline__ float exp2_fast(float x) {
  float r;
  asm("v_exp_f32 %0, %1" : "=v"(r) : "v"(x));
  return r;
}

template <int CTRL>
__device__ __forceinline__ float dpp_f(float v) {
  union { float f; int i; } u;
  u.f = v;
  u.i = __builtin_amdgcn_update_dpp(0, u.i, CTRL, 0xf, 0xf, true);
  return u.f;
}
// reduce across the 16-lane fr-group (DPP rows are 16 lanes)
__device__ __forceinline__ float rowmax16(float v) {
  v = fmaxf(v, dpp_f<0x128>(v));  // ror:8
  v = fmaxf(v, dpp_f<0x124>(v));  // ror:4
  v = fmaxf(v, dpp_f<0x4E>(v));   // quad_perm(2,3,0,1)
  v = fmaxf(v, dpp_f<0xB1>(v));   // quad_perm(1,0,3,2)
  return v;
}
__device__ __forceinline__ float rowsum16(float v) {
  v += dpp_f<0x128>(v);
  v += dpp_f<0x124>(v);
  v += dpp_f<0x4E>(v);
  v += dpp_f<0xB1>(v);
  return v;
}

__device__ __forceinline__ void gload_lds16(const void* g, void* l) {
  __builtin_amdgcn_global_load_lds(
      (const __attribute__((address_space(1))) void*)g,
      (__attribute__((address_space(3))) void*)l, 16, 0, 0);
}

// ---------------- cast fp32 -> bf16 (vectorized) ----------------
__global__ __launch_bounds__(256) void cast_bf16_kernel(
    const float* __restrict__ in, short* __restrict__ out, int n) {
  int i = (blockIdx.x * 256 + threadIdx.x) * 4;
  if (i >= n) return;
  float4 v = *(const float4*)&in[i];
  short4 o;
  o.x = f2bf(v.x); o.y = f2bf(v.y); o.z = f2bf(v.z); o.w = f2bf(v.w);
  *(short4*)&out[i] = o;
}

// ---------------- transpose + cast: [R][Cc] f32 -> [Cc][R] bf16 ----------------
__global__ __launch_bounds__(256) void transpose_cast_kernel(
    const float* __restrict__ in, short* __restrict__ out, int R, int Cc) {
  __shared__ float tile[32][33];
  const int tx = threadIdx.x, ty = threadIdx.y;  // 32 x 8
  const int c0 = blockIdx.x * 32, r0 = blockIdx.y * 32;
#pragma unroll
  for (int i = 0; i < 32; i += 8)
    tile[ty + i][tx] = in[(size_t)(r0 + ty + i) * Cc + c0 + tx];
  __syncthreads();
#pragma unroll
  for (int i = 0; i < 32; i += 8)
    out[(size_t)(c0 + ty + i) * R + r0 + tx] = f2bf(tile[tx][ty + i]);
}

// ---------------- V transpose: [BH,T,D] bf16 -> [BH,D,T] bf16 ----------------
__global__ __launch_bounds__(256) void v_transpose_kernel(
    const short* __restrict__ vb, short* __restrict__ vt) {
  __shared__ int tile[32][33];
  const int tx = threadIdx.x, ty = threadIdx.y;  // 32 x 8
  const int bh = blockIdx.z;
  const int d0 = blockIdx.x * 32, t0 = blockIdx.y * 32;
  const short* src = vb + (size_t)bh * TT * DD;
  short* dstp = vt + (size_t)bh * DD * TT;
#pragma unroll
  for (int i = 0; i < 32; i += 8)
    tile[ty + i][tx] = src[(size_t)(t0 + ty + i) * DD + d0 + tx];
  __syncthreads();
#pragma unroll
  for (int i = 0; i < 32; i += 8)
    dstp[(size_t)(d0 + ty + i) * TT + t0 + tx] = (short)tile[tx][ty + i];
}

// ---------------- bf16 MFMA GEMM, 2-phase double-buffered ----------------
// C[M,N] = A[M,K] * Bt[N,K]^T + bias. 128x128 tile, BK=32, 4 waves (2x2).
// Schedule per K-step: vmcnt(0); s_barrier; STAGE(next buf); ds_read+MFMA(cur).
// One barrier per K-step; stage loads stay in flight under the whole compute
// phase (same scheme as the verified attn kernel). XCD-chunked block swizzle.
// MODE 0: fp32 out. MODE 1: QKV scatter to [BH,T,D] bf16 (V natural; separate
// transpose kernel makes [BH,D,T]).
template <int MODE>
__global__ __launch_bounds__(256) void gemm_bf16(
    const short* __restrict__ A, const short* __restrict__ Bt,
    const float* __restrict__ bias, float* __restrict__ outF,
    short* __restrict__ outQ, short* __restrict__ outK, short* __restrict__ outV,
    int M, int N, int K) {
  __shared__ __align__(16) short As[2][128 * 32];
  __shared__ __align__(16) short Bs[2][128 * 32];
  const int tid = threadIdx.x;
  const int lane = tid & 63, wid = tid >> 6;
  const int wm = wid >> 1, wn = wid & 1;
  // XCD-chunked bijective swizzle (nwg % 8 == 0 for both call sites)
  const int nbx = N >> 7;
  const int nwg = nbx * (M >> 7);
  const int lin0 = blockIdx.x;
  const int lin = (lin0 & 7) * (nwg >> 3) + (lin0 >> 3);
  const int bx = lin % nbx, by = lin / nbx;
  const int row0 = by * 128, col0 = bx * 128;
  const int fr = lane & 15, fq = lane >> 4;
  const short* Ab = A + (size_t)row0 * K;
  const short* Bb = Bt + (size_t)col0 * K;
  const int sr = tid >> 2;
  const int so = (tid & 3) * 8;

  f32x4 acc[4][4];
#pragma unroll
  for (int m = 0; m < 4; ++m)
#pragma unroll
    for (int n = 0; n < 4; ++n) {
      f32x4 z = {0.f, 0.f, 0.f, 0.f};
      acc[m][n] = z;
    }

#define GSTAGE(c, k0)                                                          \
  do {                                                                         \
    gload_lds16(Ab + (size_t)sr * K + (k0) + so, &As[c][tid * 8]);             \
    gload_lds16(Ab + (size_t)(sr + 64) * K + (k0) + so, &As[c][2048 + tid * 8]); \
    gload_lds16(Bb + (size_t)sr * K + (k0) + so, &Bs[c][tid * 8]);             \
    gload_lds16(Bb + (size_t)(sr + 64) * K + (k0) + so, &Bs[c][2048 + tid * 8]); \
  } while (0)

  GSTAGE(0, 0);
  const int nkt = K >> 5;
  for (int kt = 0; kt < nkt; ++kt) {
    const int cur = kt & 1;
    asm volatile("s_waitcnt vmcnt(0)" ::: "memory");
    __builtin_amdgcn_s_barrier();
    if (kt + 1 < nkt) GSTAGE(cur ^ 1, (kt + 1) * 32);
    short8 a[4], b[4];
#pragma unroll
    for (int m = 0; m < 4; ++m)
      a[m] = *(const short8*)&As[cur][(wm * 64 + m * 16 + fr) * 32 + fq * 8];
#pragma unroll
    for (int n = 0; n < 4; ++n)
      b[n] = *(const short8*)&Bs[cur][(wn * 64 + n * 16 + fr) * 32 + fq * 8];
    __builtin_amdgcn_s_setprio(1);
#pragma unroll
    for (int m = 0; m < 4; ++m)
#pragma unroll
      for (int n = 0; n < 4; ++n)
        acc[m][n] = __builtin_amdgcn_mfma_f32_16x16x32_bf16(a[m], b[n], acc[m][n], 0, 0, 0);
    __builtin_amdgcn_s_setprio(0);
  }

  float bv[4];
#pragma unroll
  for (int n = 0; n < 4; ++n) bv[n] = bias[col0 + wn * 64 + n * 16 + fr];

  if (MODE == 0) {
#pragma unroll
    for (int m = 0; m < 4; ++m) {
      const int grow = row0 + wm * 64 + m * 16 + fq * 4;
#pragma unroll
      for (int n = 0; n < 4; ++n) {
        const int gcol = col0 + wn * 64 + n * 16 + fr;
#pragma unroll
        for (int r = 0; r < 4; ++r)
          outF[(size_t)(grow + r) * N + gcol] = acc[m][n][r] + bv[n];
      }
    }
  } else {
#pragma unroll
    for (int n = 0; n < 4; ++n) {
      const int gcol = col0 + wn * 64 + n * 16 + fr;
      const int which = gcol >> 10;
      const int h = (gcol & 1023) >> 6;
      const int d = gcol & 63;
      short* dst = (which == 0) ? outQ : (which == 1) ? outK : outV;
#pragma unroll
      for (int m = 0; m < 4; ++m) {
        const int grow = row0 + wm * 64 + m * 16 + fq * 4;
#pragma unroll
        for (int r = 0; r < 4; ++r) {
          const int gb = (grow + r) >> 11;
          const int gt = (grow + r) & 2047;
          const int bh = gb * HH + h;
          dst[((size_t)bh * TT + gt) * DD + d] = f2bf(acc[m][n][r] + bv[n]);
        }
      }
    }
  }
}

// ---------------- MFMA flash attention (verified r5/r8 version) ----------------
#define C2 0.18033688f  // 0.125 * log2(e)

__global__ __launch_bounds__(256) void attn_mfma_kernel(
    const short* __restrict__ q,   // [BH, T, D]
    const short* __restrict__ k,   // [BH, T, D]
    const short* __restrict__ vt,  // [BH, D, T]
    short* __restrict__ ctx) {     // [B*T, C]
  __shared__ __align__(16) short Ks[2][128 * 64];
  __shared__ __align__(16) short Vs[2][64 * 128];
  __shared__ __align__(16) short Ps[4][32 * 64];
  const int tid = threadIdx.x, lane = tid & 63, wid = tid >> 6;
  const int fr = lane & 15, fq = lane >> 4;
  const int lin = blockIdx.x;
  const int bh = lin & 63;
  const int qt = 15 - (lin >> 6);
  const int q0 = qt * 128;
  const int qw0 = q0 + wid * 32;
  const short* kbp = k + (size_t)bh * TT * DD;
  const short* vbp = vt + (size_t)bh * DD * TT;
  char* PsB = (char*)&Ps[wid][0];

#define KSB(c) ((char*)&Ks[0][0] + (c) * (128 * 64 * 2))
#define VSB(c) ((char*)&Vs[0][0] + (c) * (64 * 128 * 2))

  // Q fragments (persistent)
  short8 aq[2][2];
#pragma unroll
  for (int m = 0; m < 2; ++m)
#pragma unroll
    for (int ks = 0; ks < 2; ++ks)
      aq[m][ks] = *(const short8*)&q[((size_t)bh * TT + qw0 + m * 16 + fr) * DD + ks * 32 + fq * 8];

  float M[2][4], L[2][4];
  f32x4 o[2][4];
#pragma unroll
  for (int m = 0; m < 2; ++m)
#pragma unroll
    for (int r = 0; r < 4; ++r) { M[m][r] = -1e30f; L[m][r] = 0.f; }
#pragma unroll
  for (int m = 0; m < 2; ++m)
#pragma unroll
    for (int dg = 0; dg < 4; ++dg) {
      f32x4 z = {0.f, 0.f, 0.f, 0.f};
      o[m][dg] = z;
    }

  const int nt = qt + 1;

#define STAGE(c, tt)                                                           \
  do {                                                                         \
    const int kv0_ = (tt) * 128;                                               \
    _Pragma("unroll") for (int b_ = 0; b_ < 4; ++b_) {                         \
      const int lo_ = b_ * 4096 + tid * 16;                                    \
      const int row_ = lo_ >> 7;                                               \
      const int colb_ = lo_ & 127;                                             \
      const int src_ = colb_ ^ ((row_ & 7) << 4);                              \
      gload_lds16(kbp + ((size_t)(kv0_ + row_)) * DD + (src_ >> 1),            \
                  KSB(c) + lo_);                                               \
    }                                                                          \
    _Pragma("unroll") for (int b_ = 0; b_ < 4; ++b_) {                         \
      const int lo_ = b_ * 4096 + tid * 16;                                    \
      const int row_ = lo_ >> 8;                                               \
      const int colb_ = lo_ & 255;                                             \
      const int src_ = colb_ ^ ((row_ & 7) << 4);                              \
      gload_lds16(vbp + (size_t)row_ * TT + kv0_ + (src_ >> 1),                \
                  VSB(c) + lo_);                                               \
    }                                                                          \
  } while (0)

  STAGE(0, 0);

  for (int t = 0; t < nt; ++t) {
    const int cur = t & 1;
    asm volatile("s_waitcnt vmcnt(0)" ::: "memory");
    __builtin_amdgcn_s_barrier();
    if (t + 1 < nt) STAGE(cur ^ 1, t + 1);
    const int kv0 = t * 128;
    if (kv0 > qw0 + 31) continue;

#pragma unroll
    for (int sub = 0; sub < 2; ++sub) {
      const int kv0s = kv0 + sub * 64;
      if (kv0s > qw0 + 31) continue;
      const bool domask = (kv0s + 63 > qw0);

      // ---- QK^T ----
      short8 bk[4][2];
#pragma unroll
      for (int n = 0; n < 4; ++n) {
        const int row = sub * 64 + n * 16 + fr;
#pragma unroll
        for (int ks = 0; ks < 2; ++ks)
          bk[n][ks] = *(const short8*)(KSB(cur) + row * 128 +
                                       (((ks * 64 + fq * 16) ^ ((row & 7) << 4))));
      }
      f32x4 s[2][4];
      __builtin_amdgcn_s_setprio(1);
#pragma unroll
      for (int m = 0; m < 2; ++m)
#pragma unroll
        for (int n = 0; n < 4; ++n) {
          f32x4 z = {0.f, 0.f, 0.f, 0.f};
          s[m][n] = z;
#pragma unroll
          for (int ks = 0; ks < 2; ++ks)
            s[m][n] = __builtin_amdgcn_mfma_f32_16x16x32_bf16(aq[m][ks], bk[n][ks], s[m][n], 0, 0, 0);
        }
      __builtin_amdgcn_s_setprio(0);

      if (domask) {
#pragma unroll
        for (int m = 0; m < 2; ++m)
#pragma unroll
          for (int n = 0; n < 4; ++n)
#pragma unroll
            for (int r = 0; r < 4; ++r) {
              const int qq = qw0 + m * 16 + fq * 4 + r;
              const int kk = kv0s + n * 16 + fr;
              if (kk > qq) s[m][n][r] = -1e30f;
            }
      }

      // ---- online softmax (base-2, defer-rescale, DPP reduce) ----
#pragma unroll
      for (int m = 0; m < 2; ++m) {
        float rm2[4];
#pragma unroll
        for (int r = 0; r < 4; ++r) {
          float rm = fmaxf(fmaxf(s[m][0][r], s[m][1][r]), fmaxf(s[m][2][r], s[m][3][r]));
          rm2[r] = rowmax16(rm) * C2;
        }
        float dmax = fmaxf(fmaxf(rm2[0] - M[m][0], rm2[1] - M[m][1]),
                           fmaxf(rm2[2] - M[m][2], rm2[3] - M[m][3]));
        if (__any(dmax > 8.0f)) {
#pragma unroll
          for (int r = 0; r < 4; ++r) {
            const float Mn = fmaxf(M[m][r], rm2[r]);
            const float corr = exp2_fast(M[m][r] - Mn);
            M[m][r] = Mn;
            L[m][r] *= corr;
#pragma unroll
            for (int dg = 0; dg < 4; ++dg) o[m][dg][r] *= corr;
          }
        }
        float psum[4] = {0.f, 0.f, 0.f, 0.f};
        const int brow = m * 16 + fq * 4;
        unsigned short* pw = (unsigned short*)PsB;
#pragma unroll
        for (int n = 0; n < 4; ++n) {
          const float p0 = exp2_fast(__builtin_fmaf(s[m][n][0], C2, -M[m][0]));
          const float p1 = exp2_fast(__builtin_fmaf(s[m][n][1], C2, -M[m][1]));
          const float p2 = exp2_fast(__builtin_fmaf(s[m][n][2], C2, -M[m][2]));
          const float p3 = exp2_fast(__builtin_fmaf(s[m][n][3], C2, -M[m][3]));
          psum[0] += p0; psum[1] += p1; psum[2] += p2; psum[3] += p3;
          const unsigned u0 = cvt_pk_bf16(p0, p1);
          const unsigned u1 = cvt_pk_bf16(p2, p3);
          const int colb = n * 32 + fr * 2;
          pw[((brow + 0) * 128 + (colb ^ (((brow + 0) & 7) << 4))) >> 1] = (unsigned short)u0;
          pw[((brow + 1) * 128 + (colb ^ (((brow + 1) & 7) << 4))) >> 1] = (unsigned short)(u0 >> 16);
          pw[((brow + 2) * 128 + (colb ^ (((brow + 2) & 7) << 4))) >> 1] = (unsigned short)u1;
          pw[((brow + 3) * 128 + (colb ^ (((brow + 3) & 7) << 4))) >> 1] = (unsigned short)(u1 >> 16);
        }
#pragma unroll
        for (int r = 0; r < 4; ++r) L[m][r] += rowsum16(psum[r]);
      }

      // ---- PV ----
      short8 ap[2][2], bv[4][2];
#pragma unroll
      for (int m = 0; m < 2; ++m) {
        const int qrow = m * 16 + fr;
#pragma unroll
        for (int ks = 0; ks < 2; ++ks)
          ap[m][ks] = *(const short8*)(PsB + qrow * 128 +
                                       (((ks * 64 + fq * 16) ^ ((qrow & 7) << 4))));
      }
#pragma unroll
      for (int dg = 0; dg < 4; ++dg) {
        const int row = dg * 16 + fr;
#pragma unroll
        for (int ks = 0; ks < 2; ++ks)
          bv[dg][ks] = *(const short8*)(VSB(cur) + row * 256 +
                                        (((sub * 128 + ks * 64 + fq * 16) ^ ((row & 7) << 4))));
      }
      __builtin_amdgcn_s_setprio(1);
#pragma unroll
      for (int m = 0; m < 2; ++m)
#pragma unroll
        for (int dg = 0; dg < 4; ++dg)
#pragma unroll
          for (int ks = 0; ks < 2; ++ks)
            o[m][dg] = __builtin_amdgcn_mfma_f32_16x16x32_bf16(ap[m][ks], bv[dg][ks], o[m][dg], 0, 0, 0);
      __builtin_amdgcn_s_setprio(0);
    }
  }

  // ---- epilogue ----
  const int b = bh >> 4, h = bh & 15;
#pragma unroll
  for (int m = 0; m < 2; ++m)
#pragma unroll
    for (int dg = 0; dg < 4; ++dg)
#pragma unroll
      for (int r = 0; r < 4; ++r) {
        const int qq = qw0 + m * 16 + fq * 4 + r;
        ctx[((size_t)(b * TT + qq)) * CC + h * DD + dg * 16 + fr] =
            f2bf(o[m][dg][r] / L[m][r]);
      }
}

// ---------------- launch ----------------
extern "C" void kernel_launch(void* const* d_in, const int* in_sizes, int n_in,
                              void* d_out, int out_size, void* d_ws, size_t ws_size,
                              hipStream_t stream) {
  (void)in_sizes; (void)n_in; (void)out_size; (void)ws_size;
  const float* x = (const float*)d_in[0];
  const float* w_qkv = (const float*)d_in[1];
  const float* b_qkv = (const float*)d_in[2];
  const float* w_out = (const float*)d_in[3];
  const float* b_out = (const float*)d_in[4];
  float* out = (float*)d_out;

  char* w = (char*)d_ws;
  short* xb    = (short*)w; w += (size_t)BB * TT * CC * 2;        // 16 MB
  short* wqkvT = (short*)w; w += (size_t)3 * CC * CC * 2;         // 6 MB
  short* woutT = (short*)w; w += (size_t)CC * CC * 2;             // 2 MB
  short* qb    = (short*)w; w += (size_t)BB * HH * TT * DD * 2;   // 16 MB
  short* kb    = (short*)w; w += (size_t)BB * HH * TT * DD * 2;   // 16 MB
  short* vtb   = (short*)w; w += (size_t)BB * HH * DD * TT * 2;   // 16 MB
  short* ctx   = (short*)w; w += (size_t)BB * TT * CC * 2;        // 16 MB

  const int M = BB * TT;  // 8192

  cast_bf16_kernel<<<dim3((M * CC) / 4 / 256), dim3(256), 0, stream>>>(x, xb, M * CC);
  transpose_cast_kernel<<<dim3(3 * CC / 32, CC / 32), dim3(32, 8), 0, stream>>>(
      w_qkv, wqkvT, CC, 3 * CC);
  transpose_cast_kernel<<<dim3(CC / 32, CC / 32), dim3(32, 8), 0, stream>>>(
      w_out, woutT, CC, CC);

  // QKV projection. V (natural [BH,T,D]) goes into ctx as temp storage;
  // v_transpose then produces vtb [BH,D,T]; attn overwrites ctx afterwards.
  gemm_bf16<1><<<dim3((3 * CC / 128) * (M / 128)), dim3(256), 0, stream>>>(
      xb, wqkvT, b_qkv, nullptr, qb, kb, ctx, M, 3 * CC, CC);

  v_transpose_kernel<<<dim3(DD / 32, TT / 32, BB * HH), dim3(32, 8), 0, stream>>>(
      ctx, vtb);

  attn_mfma_kernel<<<dim3(16 * 64), dim3(256), 0, stream>>>(qb, kb, vtb, ctx);

  gemm_bf16<0><<<dim3((CC / 128) * (M / 128)), dim3(256), 0, stream>>>(
      ctx, woutT, b_out, out, nullptr, nullptr, nullptr, M, CC, CC);
}